// Round 1
// baseline (1190.503 us; speedup 1.0000x reference)
//
#include <hip/hip_runtime.h>

#define NH 16
#define HD 64
#define DM 1024
#define BB 2
#define LL 2048

// ---------------- fp32 tiled GEMM with bias: C[M,N] = A[M,K] @ B[K,N] + bias
#define TM 64
#define TN 64
#define TK 16
#define GPAD 68  // 68*4 % 16 == 0 -> 16B-aligned rows, stride%32=4 banks ok

__global__ __launch_bounds__(256) void gemm_bias_f32(
    const float* __restrict__ A, const float* __restrict__ B,
    const float* __restrict__ bias, float* __restrict__ C,
    int M, int N, int K) {
  __shared__ float As[TK][GPAD];
  __shared__ float Bs[TK][GPAD];
  const int tid = threadIdx.x;
  const int bm = blockIdx.y * TM;
  const int bn = blockIdx.x * TN;
  const int tx = tid & 15;   // -> N
  const int ty = tid >> 4;   // -> M
  float acc[4][4] = {};
  for (int k0 = 0; k0 < K; k0 += TK) {
    // A tile: 64 m x 16 k. lanes: k = tid&15 (coalesced 64B runs), m = tid>>4
#pragma unroll
    for (int p = 0; p < 4; ++p) {
      int m = (tid >> 4) + p * 16;
      int k = tid & 15;
      As[k][m] = A[(size_t)(bm + m) * K + k0 + k];
    }
    // B tile: 16 k x 64 n. lanes: n = tid&63 (coalesced 256B), k = tid>>6
#pragma unroll
    for (int p = 0; p < 4; ++p) {
      int k = (tid >> 6) + p * 4;
      int n = tid & 63;
      Bs[k][n] = B[(size_t)(k0 + k) * N + bn + n];
    }
    __syncthreads();
#pragma unroll
    for (int kk = 0; kk < TK; ++kk) {
      float af[4], bf[4];
#pragma unroll
      for (int i = 0; i < 4; ++i) af[i] = As[kk][ty * 4 + i];
#pragma unroll
      for (int j = 0; j < 4; ++j) bf[j] = Bs[kk][tx * 4 + j];
#pragma unroll
      for (int i = 0; i < 4; ++i)
#pragma unroll
        for (int j = 0; j < 4; ++j)
          acc[i][j] = fmaf(af[i], bf[j], acc[i][j]);
    }
    __syncthreads();
  }
#pragma unroll
  for (int i = 0; i < 4; ++i) {
    size_t m = (size_t)(bm + ty * 4 + i);
#pragma unroll
    for (int j = 0; j < 4; ++j) {
      int n = bn + tx * 4 + j;
      C[m * N + n] = acc[i][j] + bias[n];
    }
  }
}

// ---------------- sliding-window attention
// One workgroup (256 thr) per (b, h, 32-query tile). Keys span <=160 rows.
// LDS: Ks[160][65] (41.6 KB) + Ps[32][168] (21.5 KB) = 63.1 KB <= 64 KB.
#define QT 32
#define KT 160
#define KPAD 65   // stride%32=1: distinct kg -> distinct banks
#define PPAD 168  // stride%32=8: (qi*8+kg) distinct mod 32 on store

__global__ __launch_bounds__(256) void attn_sw(
    const float* __restrict__ qkv,  // [B*L, 3*DM]; q|k|v blocks of DM
    float* __restrict__ attnw,      // [B,NH,L,L], pre-zeroed
    float* __restrict__ ctx,        // [B*L, DM]
    const int* __restrict__ wsz_p) {
  __shared__ float Ks[KT][KPAD];
  __shared__ float Ps[QT][PPAD];
  const int wsz = *wsz_p;  // 128
  const int tid = threadIdx.x;
  const int ntile = LL / QT;                 // 64
  const int qt = blockIdx.x % ntile;
  const int h = (blockIdx.x / ntile) % NH;
  const int b = blockIdx.x / (ntile * NH);
  const int q0 = qt * QT;
  const int kmin = max(0, q0 - (wsz - 1));
  const int nk = q0 + QT - kmin;             // <=159 (wsz=128)

  // ---- stage K window into LDS (zero-fill past nk)
  {
    const int d = tid & 63;
#pragma unroll
    for (int p = 0; p < KT / 4; ++p) {
      int r = (tid >> 6) + p * 4;
      float kv = 0.f;
      if (r < nk)
        kv = qkv[(size_t)(b * LL + kmin + r) * (3 * DM) + DM + h * HD + d];
      Ks[r][d] = kv;
    }
  }
  __syncthreads();

  // ---- scores + softmax; P written to LDS (zeros at masked slots)
  {
    const int qi = tid >> 3;   // 0..31
    const int kg = tid & 7;    // key group; this thread covers kk = kg+8j
    const int q = q0 + qi;
    const float* qrow = qkv + (size_t)(b * LL + q) * (3 * DM) + h * HD;
    float s[20] = {};
#pragma unroll 8
    for (int d = 0; d < 64; ++d) {
      float qv = qrow[d];  // L1 broadcast across the octet
#pragma unroll
      for (int j = 0; j < 20; ++j)
        s[j] = fmaf(qv, Ks[kg + 8 * j][d], s[j]);
    }
    float m = -1e30f;
#pragma unroll
    for (int j = 0; j < 20; ++j) {
      int gk = kmin + kg + 8 * j;
      bool valid = (gk <= q) && (gk > q - wsz);
      s[j] = valid ? s[j] * 0.125f : -1e30f;  // 1/sqrt(64)
      m = fmaxf(m, s[j]);
    }
#pragma unroll
    for (int off = 1; off < 8; off <<= 1)
      m = fmaxf(m, __shfl_xor(m, off, 64));
    float l = 0.f;
#pragma unroll
    for (int j = 0; j < 20; ++j) {
      float e = (s[j] > -1e29f) ? __expf(s[j] - m) : 0.f;
      s[j] = e;
      l += e;
    }
#pragma unroll
    for (int off = 1; off < 8; off <<= 1)
      l += __shfl_xor(l, off, 64);
    float inv = 1.f / l;
#pragma unroll
    for (int j = 0; j < 20; ++j)
      Ps[qi][kg + 8 * j] = s[j] * inv;
  }
  __syncthreads();

  // ---- write the non-zero band of attn_weights (coalesced 512B runs)
  {
#pragma unroll
    for (int it = 0; it < 16; ++it) {
      int r = it * 2 + (tid >> 7);
      int q = q0 + r;
      int start = max(0, q - (wsz - 1));
      int c = start + (tid & 127);
      if (c <= q)
        attnw[((size_t)((b * NH + h) * LL + q)) * LL + c] = Ps[r][c - kmin];
    }
  }

  // ---- PV: V streamed from global (L2-hot), P broadcast from LDS
  {
    const int d = tid & 63;
    const int qb = tid >> 6;  // 0..3
    float acc[8] = {};
    const float* vbase = qkv + (size_t)(b * LL + kmin) * (3 * DM) + 2 * DM + h * HD + d;
    for (int kk = 0; kk < nk; ++kk) {
      float vv = vbase[(size_t)kk * (3 * DM)];
#pragma unroll
      for (int i = 0; i < 8; ++i)
        acc[i] = fmaf(Ps[qb + 4 * i][kk], vv, acc[i]);
    }
#pragma unroll
    for (int i = 0; i < 8; ++i) {
      int qi = qb + 4 * i;
      ctx[(size_t)(b * LL + q0 + qi) * DM + h * HD + d] = acc[i];
    }
  }
}

extern "C" void kernel_launch(void* const* d_in, const int* in_sizes, int n_in,
                              void* d_out, int out_size, void* d_ws, size_t ws_size,
                              hipStream_t stream) {
  const float* hs    = (const float*)d_in[0];  // [B,L,DM]
  const float* Wqkv  = (const float*)d_in[1];  // [DM, 3*DM]
  const float* bqkv  = (const float*)d_in[2];  // [3*DM]
  const float* Wproj = (const float*)d_in[3];  // [DM, DM]
  const float* bproj = (const float*)d_in[4];  // [DM]
  const int*   wszp  = (const int*)d_in[5];    // scalar window_size

  float* out   = (float*)d_out;                          // [B,L,DM]
  float* attnw = (float*)d_out + (size_t)BB * LL * DM;   // [B,NH,L,L]
  // workspace: qkv (48 MiB) + ctx (16 MiB) = 64 MiB
  float* qkv = (float*)d_ws;                             // [B*L, 3*DM]
  float* ctx = qkv + (size_t)BB * LL * 3 * DM;           // [B*L, DM]

  // zero the attention matrix; band is overwritten by attn_sw
  hipMemsetAsync(attnw, 0, (size_t)BB * NH * LL * LL * sizeof(float), stream);

  dim3 blk(256);
  // QKV projection
  dim3 g1((3 * DM) / TN, (BB * LL) / TM);
  gemm_bias_f32<<<g1, blk, 0, stream>>>(hs, Wqkv, bqkv, qkv, BB * LL, 3 * DM, DM);
  // attention
  attn_sw<<<dim3(BB * NH * (LL / QT)), blk, 0, stream>>>(qkv, attnw, ctx, wszp);
  // output projection
  dim3 g2(DM / TN, (BB * LL) / TM);
  gemm_bias_f32<<<g2, blk, 0, stream>>>(ctx, Wproj, bproj, out, BB * LL, DM, DM);
}

// Round 2
// 809.278 us; speedup vs baseline: 1.4711x; 1.4711x over previous
//
#include <hip/hip_runtime.h>
#include <stdint.h>

#define NH 16
#define HD 64
#define DM 1024
#define BB 2
#define LL 2048

typedef __bf16 bf16x8 __attribute__((ext_vector_type(8)));
typedef float f32x4 __attribute__((ext_vector_type(4)));

__device__ __forceinline__ uint16_t f2bf(float f) {
  union { float f; uint32_t u; } x{f};
  uint32_t r = (x.u + 0x7fff + ((x.u >> 16) & 1)) >> 16;
  return (uint16_t)r;
}

__device__ __forceinline__ void gload_lds16(const void* g, void* l) {
  __builtin_amdgcn_global_load_lds(
      (const __attribute__((address_space(1))) unsigned int*)g,
      (__attribute__((address_space(3))) unsigned int*)l, 16, 0, 0);
}

// ---------------- fp32 -> bf16 cast (same layout), 4 elems/thread
__global__ __launch_bounds__(256) void cvt_bf16(
    const float* __restrict__ x, uint16_t* __restrict__ y, int n4) {
  int i = blockIdx.x * 256 + threadIdx.x;
  if (i >= n4) return;
  float4 v = ((const float4*)x)[i];
  ushort4 o;
  o.x = f2bf(v.x); o.y = f2bf(v.y); o.z = f2bf(v.z); o.w = f2bf(v.w);
  ((ushort4*)y)[i] = o;
}

// ---------------- fp32 [K,N] -> bf16 [N,K] transpose-cast, 32x32 LDS tiles
__global__ __launch_bounds__(256) void transpose_cvt(
    const float* __restrict__ W, uint16_t* __restrict__ WT, int K, int N) {
  __shared__ float t[32][33];
  int bk = blockIdx.y * 32, bn = blockIdx.x * 32;
  int c = threadIdx.x & 31, r0 = threadIdx.x >> 5;  // r0: 0..7
#pragma unroll
  for (int p = 0; p < 4; ++p) {
    int r = r0 + p * 8;
    t[r][c] = W[(size_t)(bk + r) * N + bn + c];
  }
  __syncthreads();
#pragma unroll
  for (int p = 0; p < 4; ++p) {
    int r = r0 + p * 8;  // row of WT (N-dim)
    WT[(size_t)(bn + r) * K + bk + c] = f2bf(t[c][r]);
  }
}

// ---------------- bf16 MFMA GEMM (m97 structure): C[M,N] = A @ BT^T + bias
// A [M,K] bf16 row-major, BT [N,K] bf16 row-major, C fp32.
// 128x128 tile, BK=32, 256 thr = 2x2 waves, each wave 64x64 via 4x4 frags.
__global__ __launch_bounds__(256) void gemm_bt_bf16(
    const uint16_t* __restrict__ A, const uint16_t* __restrict__ BT,
    const float* __restrict__ bias, float* __restrict__ C,
    int M, int N, int K) {
  __shared__ uint16_t As[128 * 32];  // [row][k] contiguous (global_load_lds order)
  __shared__ uint16_t Bs[128 * 32];
  const int tid = threadIdx.x;
  const int bm = blockIdx.y * 128, bn = blockIdx.x * 128;
  const int lane = tid & 63, wave = tid >> 6;
  const int wr = wave >> 1, wc = wave & 1;
  f32x4 acc[4][4] = {};

  for (int k0 = 0; k0 < K; k0 += 32) {
    // stage A,B tiles: 2 chunks x 16 B per thread each
#pragma unroll
    for (int c = 0; c < 2; ++c) {
      int e = c * 2048 + tid * 8;        // bf16-element offset in tile
      int r = e >> 5, col = e & 31;
      gload_lds16(A + (size_t)(bm + r) * K + k0 + col, (char*)As + (size_t)e * 2);
      gload_lds16(BT + (size_t)(bn + r) * K + k0 + col, (char*)Bs + (size_t)e * 2);
    }
    __syncthreads();

    const int kseg = (lane >> 4) * 8;
    bf16x8 af[4], bfr[4];
#pragma unroll
    for (int i = 0; i < 4; ++i)
      af[i] = *(const bf16x8*)&As[(wr * 64 + i * 16 + (lane & 15)) * 32 + kseg];
#pragma unroll
    for (int j = 0; j < 4; ++j)
      bfr[j] = *(const bf16x8*)&Bs[(wc * 64 + j * 16 + (lane & 15)) * 32 + kseg];
#pragma unroll
    for (int i = 0; i < 4; ++i)
#pragma unroll
      for (int j = 0; j < 4; ++j)
        acc[i][j] = __builtin_amdgcn_mfma_f32_16x16x32_bf16(af[i], bfr[j], acc[i][j], 0, 0, 0);
    __syncthreads();
  }

  // epilogue: C/D layout col=lane&15, row=(lane>>4)*4+reg
#pragma unroll
  for (int i = 0; i < 4; ++i) {
#pragma unroll
    for (int j = 0; j < 4; ++j) {
      int col = bn + wc * 64 + j * 16 + (lane & 15);
      float bv = bias[col];
#pragma unroll
      for (int r = 0; r < 4; ++r) {
        int row = bm + wr * 64 + i * 16 + (lane >> 4) * 4 + r;
        C[(size_t)row * N + col] = acc[i][j][r] + bv;
      }
    }
  }
}

// ---------------- sliding-window attention (unchanged except bf16 ctx out)
#define QT 32
#define KT 160
#define KPAD 65
#define PPAD 168

__global__ __launch_bounds__(256) void attn_sw(
    const float* __restrict__ qkv,  // [B*L, 3*DM]
    float* __restrict__ attnw,      // [B,NH,L,L], pre-zeroed
    uint16_t* __restrict__ ctxb,    // [B*L, DM] bf16
    const int* __restrict__ wsz_p) {
  __shared__ float Ks[KT][KPAD];
  __shared__ float Ps[QT][PPAD];
  const int wsz = *wsz_p;  // 128
  const int tid = threadIdx.x;
  const int ntile = LL / QT;
  const int qt = blockIdx.x % ntile;
  const int h = (blockIdx.x / ntile) % NH;
  const int b = blockIdx.x / (ntile * NH);
  const int q0 = qt * QT;
  const int kmin = max(0, q0 - (wsz - 1));
  const int nk = q0 + QT - kmin;

  {
    const int d = tid & 63;
#pragma unroll
    for (int p = 0; p < KT / 4; ++p) {
      int r = (tid >> 6) + p * 4;
      float kv = 0.f;
      if (r < nk)
        kv = qkv[(size_t)(b * LL + kmin + r) * (3 * DM) + DM + h * HD + d];
      Ks[r][d] = kv;
    }
  }
  __syncthreads();

  {
    const int qi = tid >> 3;
    const int kg = tid & 7;
    const int q = q0 + qi;
    const float* qrow = qkv + (size_t)(b * LL + q) * (3 * DM) + h * HD;
    float s[20] = {};
#pragma unroll 8
    for (int d = 0; d < 64; ++d) {
      float qv = qrow[d];
#pragma unroll
      for (int j = 0; j < 20; ++j)
        s[j] = fmaf(qv, Ks[kg + 8 * j][d], s[j]);
    }
    float m = -1e30f;
#pragma unroll
    for (int j = 0; j < 20; ++j) {
      int gk = kmin + kg + 8 * j;
      bool valid = (gk <= q) && (gk > q - wsz);
      s[j] = valid ? s[j] * 0.125f : -1e30f;
      m = fmaxf(m, s[j]);
    }
#pragma unroll
    for (int off = 1; off < 8; off <<= 1)
      m = fmaxf(m, __shfl_xor(m, off, 64));
    float l = 0.f;
#pragma unroll
    for (int j = 0; j < 20; ++j) {
      float e = (s[j] > -1e29f) ? __expf(s[j] - m) : 0.f;
      s[j] = e;
      l += e;
    }
#pragma unroll
    for (int off = 1; off < 8; off <<= 1)
      l += __shfl_xor(l, off, 64);
    float inv = 1.f / l;
#pragma unroll
    for (int j = 0; j < 20; ++j)
      Ps[qi][kg + 8 * j] = s[j] * inv;
  }
  __syncthreads();

  {
#pragma unroll
    for (int it = 0; it < 16; ++it) {
      int r = it * 2 + (tid >> 7);
      int q = q0 + r;
      int start = max(0, q - (wsz - 1));
      int c = start + (tid & 127);
      if (c <= q)
        attnw[((size_t)((b * NH + h) * LL + q)) * LL + c] = Ps[r][c - kmin];
    }
  }

  {
    const int d = tid & 63;
    const int qb = tid >> 6;
    float acc[8] = {};
    const float* vbase = qkv + (size_t)(b * LL + kmin) * (3 * DM) + 2 * DM + h * HD + d;
    for (int kk = 0; kk < nk; ++kk) {
      float vv = vbase[(size_t)kk * (3 * DM)];
#pragma unroll
      for (int i = 0; i < 8; ++i)
        acc[i] = fmaf(Ps[qb + 4 * i][kk], vv, acc[i]);
    }
#pragma unroll
    for (int i = 0; i < 8; ++i) {
      int qi = qb + 4 * i;
      ctxb[(size_t)(b * LL + q0 + qi) * DM + h * HD + d] = f2bf(acc[i]);
    }
  }
}

extern "C" void kernel_launch(void* const* d_in, const int* in_sizes, int n_in,
                              void* d_out, int out_size, void* d_ws, size_t ws_size,
                              hipStream_t stream) {
  const float* hs    = (const float*)d_in[0];
  const float* Wqkv  = (const float*)d_in[1];
  const float* bqkv  = (const float*)d_in[2];
  const float* Wproj = (const float*)d_in[3];
  const float* bproj = (const float*)d_in[4];
  const int*   wszp  = (const int*)d_in[5];

  float* out   = (float*)d_out;
  float* attnw = (float*)d_out + (size_t)BB * LL * DM;

  // workspace layout (exactly 64 MiB):
  //   qkv fp32 [4096,3072]                    : 50331648 B
  //   hs_bf16 / ctx_bf16 (shared) [4096,1024] :  8388608 B
  //   WqkvT bf16 [3072,1024]                  :  6291456 B
  //   WprojT bf16 [1024,1024]                 :  2097152 B
  char* wsb = (char*)d_ws;
  float*    qkv    = (float*)wsb;
  uint16_t* hsctxb = (uint16_t*)(wsb + 50331648);
  uint16_t* WqkvT  = (uint16_t*)(wsb + 50331648 + 8388608);
  uint16_t* WprojT = (uint16_t*)(wsb + 50331648 + 8388608 + 6291456);

  hipMemsetAsync(attnw, 0, (size_t)BB * NH * LL * LL * sizeof(float), stream);

  dim3 blk(256);
  // convert inputs to bf16 (W transposed so both GEMM operands are K-major)
  cvt_bf16<<<dim3((BB * LL * DM / 4 + 255) / 256), blk, 0, stream>>>(hs, hsctxb, BB * LL * DM / 4);
  transpose_cvt<<<dim3(3 * DM / 32, DM / 32), blk, 0, stream>>>(Wqkv, WqkvT, DM, 3 * DM);
  transpose_cvt<<<dim3(DM / 32, DM / 32), blk, 0, stream>>>(Wproj, WprojT, DM, DM);

  // QKV projection: [4096,1024] @ [1024,3072] + b -> qkv
  gemm_bt_bf16<<<dim3(3 * DM / 128, BB * LL / 128), blk, 0, stream>>>(
      hsctxb, WqkvT, bqkv, qkv, BB * LL, 3 * DM, DM);

  // attention (fp32 scores/softmax), ctx written as bf16 into shared slot
  attn_sw<<<dim3(BB * NH * (LL / QT)), blk, 0, stream>>>(qkv, attnw, hsctxb, wszp);

  // output projection: [4096,1024] @ [1024,1024] + b -> out
  gemm_bt_bf16<<<dim3(DM / 128, BB * LL / 128), blk, 0, stream>>>(
      hsctxb, WprojT, bproj, out, BB * LL, DM, DM);
}

// Round 3
// 751.186 us; speedup vs baseline: 1.5848x; 1.0773x over previous
//
#include <hip/hip_runtime.h>
#include <stdint.h>

#define NH 16
#define HD 64
#define DM 1024
#define BB 2
#define LL 2048

typedef __bf16 bf16x8 __attribute__((ext_vector_type(8)));
typedef float f32x4 __attribute__((ext_vector_type(4)));

__device__ __forceinline__ uint16_t f2bf(float f) {
  union { float f; uint32_t u; } x{f};
  uint32_t r = (x.u + 0x7fff + ((x.u >> 16) & 1)) >> 16;
  return (uint16_t)r;
}

__device__ __forceinline__ void gload_lds16(const void* g, void* l) {
  __builtin_amdgcn_global_load_lds(
      (const __attribute__((address_space(1))) unsigned int*)g,
      (__attribute__((address_space(3))) unsigned int*)l, 16, 0, 0);
}

// ---------------- efficient zero fill (the rocclr fill kernel has ~4x HBM
// write amplification; this hits ~6 TB/s with clean 16B stores)
__global__ __launch_bounds__(256) void zero4(float4* __restrict__ p) {
  size_t base = (size_t)blockIdx.x * 1024 + threadIdx.x;
  float4 z = {0.f, 0.f, 0.f, 0.f};
#pragma unroll
  for (int k = 0; k < 4; ++k) p[base + k * 256] = z;
}

// ---------------- fp32 -> bf16 cast (same layout), 4 elems/thread
__global__ __launch_bounds__(256) void cvt_bf16(
    const float* __restrict__ x, uint16_t* __restrict__ y, int n4) {
  int i = blockIdx.x * 256 + threadIdx.x;
  if (i >= n4) return;
  float4 v = ((const float4*)x)[i];
  ushort4 o;
  o.x = f2bf(v.x); o.y = f2bf(v.y); o.z = f2bf(v.z); o.w = f2bf(v.w);
  ((ushort4*)y)[i] = o;
}

// ---------------- fp32 [K,N] -> bf16 [N,K] transpose-cast, 32x32 LDS tiles
__global__ __launch_bounds__(256) void transpose_cvt(
    const float* __restrict__ W, uint16_t* __restrict__ WT, int K, int N) {
  __shared__ float t[32][33];
  int bk = blockIdx.y * 32, bn = blockIdx.x * 32;
  int c = threadIdx.x & 31, r0 = threadIdx.x >> 5;
#pragma unroll
  for (int p = 0; p < 4; ++p) {
    int r = r0 + p * 8;
    t[r][c] = W[(size_t)(bk + r) * N + bn + c];
  }
  __syncthreads();
#pragma unroll
  for (int p = 0; p < 4; ++p) {
    int r = r0 + p * 8;
    WT[(size_t)(bn + r) * K + bk + c] = f2bf(t[c][r]);
  }
}

// ---------------- bf16 MFMA GEMM (m97 structure): C[M,N] = A @ BT^T + bias
__global__ __launch_bounds__(256) void gemm_bt_bf16(
    const uint16_t* __restrict__ A, const uint16_t* __restrict__ BT,
    const float* __restrict__ bias, float* __restrict__ C,
    int M, int N, int K) {
  __shared__ uint16_t As[128 * 32];
  __shared__ uint16_t Bs[128 * 32];
  const int tid = threadIdx.x;
  const int bm = blockIdx.y * 128, bn = blockIdx.x * 128;
  const int lane = tid & 63, wave = tid >> 6;
  const int wr = wave >> 1, wc = wave & 1;
  f32x4 acc[4][4] = {};

  for (int k0 = 0; k0 < K; k0 += 32) {
#pragma unroll
    for (int c = 0; c < 2; ++c) {
      int e = c * 2048 + tid * 8;
      int r = e >> 5, col = e & 31;
      gload_lds16(A + (size_t)(bm + r) * K + k0 + col, (char*)As + (size_t)e * 2);
      gload_lds16(BT + (size_t)(bn + r) * K + k0 + col, (char*)Bs + (size_t)e * 2);
    }
    __syncthreads();

    const int kseg = (lane >> 4) * 8;
    bf16x8 af[4], bfr[4];
#pragma unroll
    for (int i = 0; i < 4; ++i)
      af[i] = *(const bf16x8*)&As[(wr * 64 + i * 16 + (lane & 15)) * 32 + kseg];
#pragma unroll
    for (int j = 0; j < 4; ++j)
      bfr[j] = *(const bf16x8*)&Bs[(wc * 64 + j * 16 + (lane & 15)) * 32 + kseg];
#pragma unroll
    for (int i = 0; i < 4; ++i)
#pragma unroll
      for (int j = 0; j < 4; ++j)
        acc[i][j] = __builtin_amdgcn_mfma_f32_16x16x32_bf16(af[i], bfr[j], acc[i][j], 0, 0, 0);
    __syncthreads();
  }

#pragma unroll
  for (int i = 0; i < 4; ++i) {
#pragma unroll
    for (int j = 0; j < 4; ++j) {
      int col = bn + wc * 64 + j * 16 + (lane & 15);
      float bv = bias[col];
#pragma unroll
      for (int r = 0; r < 4; ++r) {
        int row = bm + wr * 64 + i * 16 + (lane >> 4) * 4 + r;
        C[(size_t)row * N + col] = acc[i][j][r] + bv;
      }
    }
  }
}

// ---------------- sliding-window attention, b128 LDS access
#define QT 32
#define KT 160
#define KPAD 68   // floats; 272B row stride: 16B-aligned, kg->distinct 4-bank groups
#define PPAD 168  // floats; 672B row stride: 16B-aligned

__global__ __launch_bounds__(256) void attn_sw(
    const float* __restrict__ qkv,  // [B*L, 3*DM]
    float* __restrict__ attnw,      // [B,NH,L,L], pre-zeroed by zero4
    uint16_t* __restrict__ ctxb,    // [B*L, DM] bf16
    const int* __restrict__ wsz_p) {
  __shared__ float Ks[KT][KPAD];
  __shared__ float Ps[QT][PPAD];
  const int wsz = *wsz_p;  // 128
  const int tid = threadIdx.x;
  const int ntile = LL / QT;
  const int qt = blockIdx.x % ntile;
  const int h = (blockIdx.x / ntile) % NH;
  const int b = blockIdx.x / (ntile * NH);
  const int q0 = qt * QT;
  const int kmin = max(0, q0 - (wsz - 1));
  const int nk = q0 + QT - kmin;  // <=159

  // ---- stage K window: float4 loads, 16 rows per 256-thread step
  {
    const int c4 = (tid & 15) * 4;
    const int r0 = tid >> 4;
#pragma unroll
    for (int p = 0; p < KT / 16; ++p) {
      int r = r0 + p * 16;
      float4 kv = {0.f, 0.f, 0.f, 0.f};
      if (r < nk)
        kv = *(const float4*)&qkv[(size_t)(b * LL + kmin + r) * (3 * DM) + DM + h * HD + c4];
      *(float4*)&Ks[r][c4] = kv;
    }
  }
  __syncthreads();

  // ---- scores + softmax (fp32), float4 over d
  {
    const int qi = tid >> 3;
    const int kg = tid & 7;
    const int q = q0 + qi;
    const float4* qrow4 = (const float4*)(qkv + (size_t)(b * LL + q) * (3 * DM) + h * HD);
    float s[20] = {};
#pragma unroll 4
    for (int d4 = 0; d4 < 16; ++d4) {
      float4 qv = qrow4[d4];
#pragma unroll
      for (int j = 0; j < 20; ++j) {
        float4 kv = *(const float4*)&Ks[kg + 8 * j][d4 * 4];
        s[j] = fmaf(qv.x, kv.x, fmaf(qv.y, kv.y, fmaf(qv.z, kv.z, fmaf(qv.w, kv.w, s[j]))));
      }
    }
    float m = -1e30f;
#pragma unroll
    for (int j = 0; j < 20; ++j) {
      int gk = kmin + kg + 8 * j;
      bool valid = (gk <= q) && (gk > q - wsz);
      s[j] = valid ? s[j] * 0.125f : -1e30f;
      m = fmaxf(m, s[j]);
    }
#pragma unroll
    for (int off = 1; off < 8; off <<= 1)
      m = fmaxf(m, __shfl_xor(m, off, 64));
    float l = 0.f;
#pragma unroll
    for (int j = 0; j < 20; ++j) {
      float e = (s[j] > -1e29f) ? __expf(s[j] - m) : 0.f;
      s[j] = e;
      l += e;
    }
#pragma unroll
    for (int off = 1; off < 8; off <<= 1)
      l += __shfl_xor(l, off, 64);
    float inv = 1.f / l;
#pragma unroll
    for (int j = 0; j < 20; ++j)
      Ps[qi][kg + 8 * j] = s[j] * inv;
  }
  __syncthreads();

  // ---- write the non-zero band of attn_weights
  {
#pragma unroll
    for (int it = 0; it < 16; ++it) {
      int r = it * 2 + (tid >> 7);
      int q = q0 + r;
      int start = max(0, q - (wsz - 1));
      int c = start + (tid & 127);
      if (c <= q)
        attnw[((size_t)((b * NH + h) * LL + q)) * LL + c] = Ps[r][c - kmin];
    }
  }

  // ---- PV: V streamed from global, Ps read as float4 (all-lane broadcast)
  {
    const int d = tid & 63;
    const int qb = tid >> 6;
    float acc[8] = {};
    const float* vbase = qkv + (size_t)(b * LL + kmin) * (3 * DM) + 2 * DM + h * HD + d;
#pragma unroll 2
    for (int kk4 = 0; kk4 < KT / 4; ++kk4) {
      // Ps cols >= nk are exact zeros, so over-reading V rows is harmless
      float v0 = vbase[(size_t)(4 * kk4 + 0) * (3 * DM)];
      float v1 = vbase[(size_t)(4 * kk4 + 1) * (3 * DM)];
      float v2 = vbase[(size_t)(4 * kk4 + 2) * (3 * DM)];
      float v3 = vbase[(size_t)(4 * kk4 + 3) * (3 * DM)];
#pragma unroll
      for (int i = 0; i < 8; ++i) {
        float4 p = *(const float4*)&Ps[qb + 4 * i][kk4 * 4];
        acc[i] = fmaf(p.x, v0, fmaf(p.y, v1, fmaf(p.z, v2, fmaf(p.w, v3, acc[i]))));
      }
    }
#pragma unroll
    for (int i = 0; i < 8; ++i) {
      int qi = qb + 4 * i;
      ctxb[(size_t)(b * LL + q0 + qi) * DM + h * HD + d] = f2bf(acc[i]);
    }
  }
}

extern "C" void kernel_launch(void* const* d_in, const int* in_sizes, int n_in,
                              void* d_out, int out_size, void* d_ws, size_t ws_size,
                              hipStream_t stream) {
  const float* hs    = (const float*)d_in[0];
  const float* Wqkv  = (const float*)d_in[1];
  const float* bqkv  = (const float*)d_in[2];
  const float* Wproj = (const float*)d_in[3];
  const float* bproj = (const float*)d_in[4];
  const int*   wszp  = (const int*)d_in[5];

  float* out   = (float*)d_out;
  float* attnw = (float*)d_out + (size_t)BB * LL * DM;

  char* wsb = (char*)d_ws;
  float*    qkv    = (float*)wsb;                              // 50331648 B
  uint16_t* hsctxb = (uint16_t*)(wsb + 50331648);              //  8388608 B
  uint16_t* WqkvT  = (uint16_t*)(wsb + 50331648 + 8388608);    //  6291456 B
  uint16_t* WprojT = (uint16_t*)(wsb + 50331648 + 8388608 + 6291456);

  dim3 blk(256);

  // zero attn_weights with clean float4 stores (NOT hipMemsetAsync: the
  // rocclr fill kernel shows 4x HBM write amplification, ~350us vs ~90us)
  // total float4s: 2*16*2048*2048/4 = 33554432 -> 32768 blocks x 1024 each
  zero4<<<dim3(32768), blk, 0, stream>>>((float4*)attnw);

  cvt_bf16<<<dim3((BB * LL * DM / 4 + 255) / 256), blk, 0, stream>>>(hs, hsctxb, BB * LL * DM / 4);
  transpose_cvt<<<dim3(3 * DM / 32, DM / 32), blk, 0, stream>>>(Wqkv, WqkvT, DM, 3 * DM);
  transpose_cvt<<<dim3(DM / 32, DM / 32), blk, 0, stream>>>(Wproj, WprojT, DM, DM);

  gemm_bt_bf16<<<dim3(3 * DM / 128, BB * LL / 128), blk, 0, stream>>>(
      hsctxb, WqkvT, bqkv, qkv, BB * LL, 3 * DM, DM);

  attn_sw<<<dim3(BB * NH * (LL / QT)), blk, 0, stream>>>(qkv, attnw, hsctxb, wszp);

  gemm_bt_bf16<<<dim3(DM / 128, BB * LL / 128), blk, 0, stream>>>(
      hsctxb, WprojT, bproj, out, BB * LL, DM, DM);
}

// Round 4
// 722.747 us; speedup vs baseline: 1.6472x; 1.0393x over previous
//
#include <hip/hip_runtime.h>
#include <stdint.h>

#define NH 16
#define HD 64
#define DM 1024
#define BB 2
#define LL 2048

typedef __bf16 bf16x8 __attribute__((ext_vector_type(8)));
typedef float f32x4 __attribute__((ext_vector_type(4)));

__device__ __forceinline__ uint16_t f2bf(float f) {
  union { float f; uint32_t u; } x{f};
  uint32_t r = (x.u + 0x7fff + ((x.u >> 16) & 1)) >> 16;
  return (uint16_t)r;
}

__device__ __forceinline__ void gload_lds16(const void* g, void* l) {
  __builtin_amdgcn_global_load_lds(
      (const __attribute__((address_space(1))) unsigned int*)g,
      (__attribute__((address_space(3))) unsigned int*)l, 16, 0, 0);
}

// ---------------- fp32 -> bf16 cast (same layout), 4 elems/thread
__global__ __launch_bounds__(256) void cvt_bf16(
    const float* __restrict__ x, uint16_t* __restrict__ y, int n4) {
  int i = blockIdx.x * 256 + threadIdx.x;
  if (i >= n4) return;
  float4 v = ((const float4*)x)[i];
  ushort4 o;
  o.x = f2bf(v.x); o.y = f2bf(v.y); o.z = f2bf(v.z); o.w = f2bf(v.w);
  ((ushort4*)y)[i] = o;
}

// ---------------- fp32 [K,N] -> bf16 [N,K] transpose-cast, 32x32 LDS tiles
__global__ __launch_bounds__(256) void transpose_cvt(
    const float* __restrict__ W, uint16_t* __restrict__ WT, int K, int N) {
  __shared__ float t[32][33];
  int bk = blockIdx.y * 32, bn = blockIdx.x * 32;
  int c = threadIdx.x & 31, r0 = threadIdx.x >> 5;
#pragma unroll
  for (int p = 0; p < 4; ++p) {
    int r = r0 + p * 8;
    t[r][c] = W[(size_t)(bk + r) * N + bn + c];
  }
  __syncthreads();
#pragma unroll
  for (int p = 0; p < 4; ++p) {
    int r = r0 + p * 8;
    WT[(size_t)(bn + r) * K + bk + c] = f2bf(t[c][r]);
  }
}

// ---------------- bf16 MFMA GEMM (m97 structure): C[M,N] = A @ BT^T + bias
__global__ __launch_bounds__(256) void gemm_bt_bf16(
    const uint16_t* __restrict__ A, const uint16_t* __restrict__ BT,
    const float* __restrict__ bias, float* __restrict__ C,
    int M, int N, int K) {
  __shared__ uint16_t As[128 * 32];
  __shared__ uint16_t Bs[128 * 32];
  const int tid = threadIdx.x;
  const int bm = blockIdx.y * 128, bn = blockIdx.x * 128;
  const int lane = tid & 63, wave = tid >> 6;
  const int wr = wave >> 1, wc = wave & 1;
  f32x4 acc[4][4] = {};

  for (int k0 = 0; k0 < K; k0 += 32) {
#pragma unroll
    for (int c = 0; c < 2; ++c) {
      int e = c * 2048 + tid * 8;
      int r = e >> 5, col = e & 31;
      gload_lds16(A + (size_t)(bm + r) * K + k0 + col, (char*)As + (size_t)e * 2);
      gload_lds16(BT + (size_t)(bn + r) * K + k0 + col, (char*)Bs + (size_t)e * 2);
    }
    __syncthreads();

    const int kseg = (lane >> 4) * 8;
    bf16x8 af[4], bfr[4];
#pragma unroll
    for (int i = 0; i < 4; ++i)
      af[i] = *(const bf16x8*)&As[(wr * 64 + i * 16 + (lane & 15)) * 32 + kseg];
#pragma unroll
    for (int j = 0; j < 4; ++j)
      bfr[j] = *(const bf16x8*)&Bs[(wc * 64 + j * 16 + (lane & 15)) * 32 + kseg];
#pragma unroll
    for (int i = 0; i < 4; ++i)
#pragma unroll
      for (int j = 0; j < 4; ++j)
        acc[i][j] = __builtin_amdgcn_mfma_f32_16x16x32_bf16(af[i], bfr[j], acc[i][j], 0, 0, 0);
    __syncthreads();
  }

#pragma unroll
  for (int i = 0; i < 4; ++i) {
#pragma unroll
    for (int j = 0; j < 4; ++j) {
      int col = bn + wc * 64 + j * 16 + (lane & 15);
      float bv = bias[col];
#pragma unroll
      for (int r = 0; r < 4; ++r) {
        int row = bm + wr * 64 + i * 16 + (lane >> 4) * 4 + r;
        C[(size_t)row * N + col] = acc[i][j][r] + bv;
      }
    }
  }
}

// ---------------- sliding-window attention with fused full-row attnw writes
// Key window re-based at kbase = kmin & ~31 so Ps columns are 4-aligned with
// absolute key columns; Ps entries outside the valid causal window are exact
// zeros, so writing the full 2048-col row from {0 | Ps} needs no zero4 pass.
#define QT 32
#define KT 160
#define KPAD 68   // floats; 272B row stride: 16B-aligned, conflict-free groups
#define PPAD 168  // floats; 672B row stride: 16B-aligned

__global__ __launch_bounds__(256) void attn_sw(
    const float* __restrict__ qkv,  // [B*L, 3*DM]
    float* __restrict__ attnw,      // [B,NH,L,L] - fully written here
    uint16_t* __restrict__ ctxb,    // [B*L, DM] bf16
    const int* __restrict__ wsz_p) {
  __shared__ float Ks[KT][KPAD];
  __shared__ float Ps[QT][PPAD];
  const int wsz = *wsz_p;  // 128
  const int tid = threadIdx.x;
  const int ntile = LL / QT;
  const int qt = blockIdx.x % ntile;
  const int h = (blockIdx.x / ntile) % NH;
  const int b = blockIdx.x / (ntile * NH);
  const int q0 = qt * QT;
  const int kmin = max(0, q0 - (wsz - 1));
  const int kbase = kmin & ~31;        // 32-aligned window base
  const int nk = q0 + QT - kbase;      // <=160, rows [kbase, q0+32)

  // ---- stage K window: float4 loads, 16 rows per 256-thread step
  {
    const int c4 = (tid & 15) * 4;
    const int r0 = tid >> 4;
#pragma unroll
    for (int p = 0; p < KT / 16; ++p) {
      int r = r0 + p * 16;
      float4 kv = {0.f, 0.f, 0.f, 0.f};
      if (r < nk)
        kv = *(const float4*)&qkv[(size_t)(b * LL + kbase + r) * (3 * DM) + DM + h * HD + c4];
      *(float4*)&Ks[r][c4] = kv;
    }
  }
  __syncthreads();

  // ---- scores + softmax (fp32), float4 over d
  {
    const int qi = tid >> 3;
    const int kg = tid & 7;
    const int q = q0 + qi;
    const float4* qrow4 = (const float4*)(qkv + (size_t)(b * LL + q) * (3 * DM) + h * HD);
    float s[20] = {};
#pragma unroll 4
    for (int d4 = 0; d4 < 16; ++d4) {
      float4 qv = qrow4[d4];
#pragma unroll
      for (int j = 0; j < 20; ++j) {
        float4 kv = *(const float4*)&Ks[kg + 8 * j][d4 * 4];
        s[j] = fmaf(qv.x, kv.x, fmaf(qv.y, kv.y, fmaf(qv.z, kv.z, fmaf(qv.w, kv.w, s[j]))));
      }
    }
    float m = -1e30f;
#pragma unroll
    for (int j = 0; j < 20; ++j) {
      int gk = kbase + kg + 8 * j;
      bool valid = (gk <= q) && (gk > q - wsz);
      s[j] = valid ? s[j] * 0.125f : -1e30f;
      m = fmaxf(m, s[j]);
    }
#pragma unroll
    for (int off = 1; off < 8; off <<= 1)
      m = fmaxf(m, __shfl_xor(m, off, 64));
    float l = 0.f;
#pragma unroll
    for (int j = 0; j < 20; ++j) {
      float e = (s[j] > -1e29f) ? __expf(s[j] - m) : 0.f;
      s[j] = e;
      l += e;
    }
#pragma unroll
    for (int off = 1; off < 8; off <<= 1)
      l += __shfl_xor(l, off, 64);
    float inv = 1.f / l;
#pragma unroll
    for (int j = 0; j < 20; ++j)
      Ps[qi][kg + 8 * j] = s[j] * inv;
  }
  __syncthreads();

  // ---- write FULL attnw rows (zeros + prob band), coalesced float4
  {
#pragma unroll
    for (int it = 0; it < 16; ++it) {
      int r = it * 2 + (tid >> 7);             // 0..31
      size_t rowoff = ((size_t)((b * NH + h) * LL + q0 + r)) * LL;
      int cb = (tid & 127) * 4;                // 0..508
#pragma unroll
      for (int jj = 0; jj < 4; ++jj) {
        int c4 = cb + jj * 512;
        float4 v = {0.f, 0.f, 0.f, 0.f};
        int pc = c4 - kbase;
        if (pc >= 0 && pc < KT)
          v = *(const float4*)&Ps[r][pc];
        *(float4*)&attnw[rowoff + c4] = v;
      }
    }
  }

  // ---- PV: V streamed from global, Ps read as float4 (all-lane broadcast)
  {
    const int d = tid & 63;
    const int qb = tid >> 6;
    float acc[8] = {};
    const float* vbase = qkv + (size_t)(b * LL + kbase) * (3 * DM) + 2 * DM + h * HD + d;
#pragma unroll 2
    for (int kk4 = 0; kk4 < KT / 4; ++kk4) {
      // Ps cols >= nk are exact zeros; rows kbase..kbase+159 <= q0+31 in range
      float v0 = vbase[(size_t)(4 * kk4 + 0) * (3 * DM)];
      float v1 = vbase[(size_t)(4 * kk4 + 1) * (3 * DM)];
      float v2 = vbase[(size_t)(4 * kk4 + 2) * (3 * DM)];
      float v3 = vbase[(size_t)(4 * kk4 + 3) * (3 * DM)];
#pragma unroll
      for (int i = 0; i < 8; ++i) {
        float4 p = *(const float4*)&Ps[qb + 4 * i][kk4 * 4];
        acc[i] = fmaf(p.x, v0, fmaf(p.y, v1, fmaf(p.z, v2, fmaf(p.w, v3, acc[i]))));
      }
    }
#pragma unroll
    for (int i = 0; i < 8; ++i) {
      int qi = qb + 4 * i;
      ctxb[(size_t)(b * LL + q0 + qi) * DM + h * HD + d] = f2bf(acc[i]);
    }
  }
}

extern "C" void kernel_launch(void* const* d_in, const int* in_sizes, int n_in,
                              void* d_out, int out_size, void* d_ws, size_t ws_size,
                              hipStream_t stream) {
  const float* hs    = (const float*)d_in[0];
  const float* Wqkv  = (const float*)d_in[1];
  const float* bqkv  = (const float*)d_in[2];
  const float* Wproj = (const float*)d_in[3];
  const float* bproj = (const float*)d_in[4];
  const int*   wszp  = (const int*)d_in[5];

  float* out   = (float*)d_out;
  float* attnw = (float*)d_out + (size_t)BB * LL * DM;

  char* wsb = (char*)d_ws;
  float*    qkv    = (float*)wsb;                              // 50331648 B
  uint16_t* hsctxb = (uint16_t*)(wsb + 50331648);              //  8388608 B
  uint16_t* WqkvT  = (uint16_t*)(wsb + 50331648 + 8388608);    //  6291456 B
  uint16_t* WprojT = (uint16_t*)(wsb + 50331648 + 8388608 + 6291456);

  dim3 blk(256);

  cvt_bf16<<<dim3((BB * LL * DM / 4 + 255) / 256), blk, 0, stream>>>(hs, hsctxb, BB * LL * DM / 4);
  transpose_cvt<<<dim3(3 * DM / 32, DM / 32), blk, 0, stream>>>(Wqkv, WqkvT, DM, 3 * DM);
  transpose_cvt<<<dim3(DM / 32, DM / 32), blk, 0, stream>>>(Wproj, WprojT, DM, DM);

  gemm_bt_bf16<<<dim3(3 * DM / 128, BB * LL / 128), blk, 0, stream>>>(
      hsctxb, WqkvT, bqkv, qkv, BB * LL, 3 * DM, DM);

  // attn_sw now writes ALL of attnw (zeros + band) itself - no zero pass
  attn_sw<<<dim3(BB * NH * (LL / QT)), blk, 0, stream>>>(qkv, attnw, hsctxb, wszp);

  gemm_bt_bf16<<<dim3(DM / 128, BB * LL / 128), blk, 0, stream>>>(
      hsctxb, WprojT, bproj, out, BB * LL, DM, DM);
}

// Round 5
// 695.498 us; speedup vs baseline: 1.7117x; 1.0392x over previous
//
#include <hip/hip_runtime.h>
#include <stdint.h>

#define NH 16
#define HD 64
#define DM 1024
#define BB 2
#define LL 2048

typedef __bf16 bf16x8 __attribute__((ext_vector_type(8)));
typedef float f32x4 __attribute__((ext_vector_type(4)));

__device__ __forceinline__ uint16_t f2bf(float f) {
  union { float f; uint32_t u; } x{f};
  uint32_t r = (x.u + 0x7fff + ((x.u >> 16) & 1)) >> 16;
  return (uint16_t)r;
}

__device__ __forceinline__ void gload_lds16(const void* g, void* l) {
  __builtin_amdgcn_global_load_lds(
      (const __attribute__((address_space(1))) unsigned int*)g,
      (__attribute__((address_space(3))) unsigned int*)l, 16, 0, 0);
}

// ---------------- fp32 -> bf16 cast (same layout), 4 elems/thread
__global__ __launch_bounds__(256) void cvt_bf16(
    const float* __restrict__ x, uint16_t* __restrict__ y, int n4) {
  int i = blockIdx.x * 256 + threadIdx.x;
  if (i >= n4) return;
  float4 v = ((const float4*)x)[i];
  ushort4 o;
  o.x = f2bf(v.x); o.y = f2bf(v.y); o.z = f2bf(v.z); o.w = f2bf(v.w);
  ((ushort4*)y)[i] = o;
}

// ---------------- fp32 [K,N] -> bf16 [N,K] transpose-cast, 32x32 LDS tiles
__global__ __launch_bounds__(256) void transpose_cvt(
    const float* __restrict__ W, uint16_t* __restrict__ WT, int K, int N) {
  __shared__ float t[32][33];
  int bk = blockIdx.y * 32, bn = blockIdx.x * 32;
  int c = threadIdx.x & 31, r0 = threadIdx.x >> 5;
#pragma unroll
  for (int p = 0; p < 4; ++p) {
    int r = r0 + p * 8;
    t[r][c] = W[(size_t)(bk + r) * N + bn + c];
  }
  __syncthreads();
#pragma unroll
  for (int p = 0; p < 4; ++p) {
    int r = r0 + p * 8;
    WT[(size_t)(bn + r) * K + bk + c] = f2bf(t[c][r]);
  }
}

// ---------------- bf16 MFMA GEMM (m97 structure): C[M,N] = A @ BT^T + bias
__global__ __launch_bounds__(256) void gemm_bt_bf16(
    const uint16_t* __restrict__ A, const uint16_t* __restrict__ BT,
    const float* __restrict__ bias, float* __restrict__ C,
    int M, int N, int K) {
  __shared__ uint16_t As[128 * 32];
  __shared__ uint16_t Bs[128 * 32];
  const int tid = threadIdx.x;
  const int bm = blockIdx.y * 128, bn = blockIdx.x * 128;
  const int lane = tid & 63, wave = tid >> 6;
  const int wr = wave >> 1, wc = wave & 1;
  f32x4 acc[4][4] = {};

  for (int k0 = 0; k0 < K; k0 += 32) {
#pragma unroll
    for (int c = 0; c < 2; ++c) {
      int e = c * 2048 + tid * 8;
      int r = e >> 5, col = e & 31;
      gload_lds16(A + (size_t)(bm + r) * K + k0 + col, (char*)As + (size_t)e * 2);
      gload_lds16(BT + (size_t)(bn + r) * K + k0 + col, (char*)Bs + (size_t)e * 2);
    }
    __syncthreads();

    const int kseg = (lane >> 4) * 8;
    bf16x8 af[4], bfr[4];
#pragma unroll
    for (int i = 0; i < 4; ++i)
      af[i] = *(const bf16x8*)&As[(wr * 64 + i * 16 + (lane & 15)) * 32 + kseg];
#pragma unroll
    for (int j = 0; j < 4; ++j)
      bfr[j] = *(const bf16x8*)&Bs[(wc * 64 + j * 16 + (lane & 15)) * 32 + kseg];
#pragma unroll
    for (int i = 0; i < 4; ++i)
#pragma unroll
      for (int j = 0; j < 4; ++j)
        acc[i][j] = __builtin_amdgcn_mfma_f32_16x16x32_bf16(af[i], bfr[j], acc[i][j], 0, 0, 0);
    __syncthreads();
  }

#pragma unroll
  for (int i = 0; i < 4; ++i) {
#pragma unroll
    for (int j = 0; j < 4; ++j) {
      int col = bn + wc * 64 + j * 16 + (lane & 15);
      float bv = bias[col];
#pragma unroll
      for (int r = 0; r < 4; ++r) {
        int row = bm + wr * 64 + i * 16 + (lane >> 4) * 4 + r;
        C[(size_t)row * N + col] = acc[i][j][r] + bv;
      }
    }
  }
}

// ---------------- sliding-window attention with fused full-row attnw writes
#define QT 32
#define KT 160
#define KPAD 68
#define PPAD 168

__global__ __launch_bounds__(256) void attn_sw(
    const float* __restrict__ qkv,  // [B*L, 3*DM]
    float* __restrict__ attnw,      // [B,NH,L,L] - fully written here
    uint16_t* __restrict__ ctxb,    // [B*L, DM] bf16
    const int* __restrict__ wsz_p) {
  __shared__ float Ks[KT][KPAD];
  __shared__ float Ps[QT][PPAD];
  const int wsz = *wsz_p;  // 128
  const int tid = threadIdx.x;
  const int ntile = LL / QT;
  const int qt = blockIdx.x % ntile;
  const int h = (blockIdx.x / ntile) % NH;
  const int b = blockIdx.x / (ntile * NH);
  const int q0 = qt * QT;
  const int kmin = max(0, q0 - (wsz - 1));
  const int kbase = kmin & ~31;        // 32-aligned window base
  const int nk = q0 + QT - kbase;      // <=160

  // ---- stage K window: float4 loads
  {
    const int c4 = (tid & 15) * 4;
    const int r0 = tid >> 4;
#pragma unroll
    for (int p = 0; p < KT / 16; ++p) {
      int r = r0 + p * 16;
      float4 kv = {0.f, 0.f, 0.f, 0.f};
      if (r < nk)
        kv = *(const float4*)&qkv[(size_t)(b * LL + kbase + r) * (3 * DM) + DM + h * HD + c4];
      *(float4*)&Ks[r][c4] = kv;
    }
  }
  __syncthreads();

  // ---- scores + softmax (fp32)
  {
    const int qi = tid >> 3;
    const int kg = tid & 7;
    const int q = q0 + qi;
    const float4* qrow4 = (const float4*)(qkv + (size_t)(b * LL + q) * (3 * DM) + h * HD);
    float s[20] = {};
#pragma unroll 4
    for (int d4 = 0; d4 < 16; ++d4) {
      float4 qv = qrow4[d4];
#pragma unroll
      for (int j = 0; j < 20; ++j) {
        float4 kv = *(const float4*)&Ks[kg + 8 * j][d4 * 4];
        s[j] = fmaf(qv.x, kv.x, fmaf(qv.y, kv.y, fmaf(qv.z, kv.z, fmaf(qv.w, kv.w, s[j]))));
      }
    }
    float m = -1e30f;
#pragma unroll
    for (int j = 0; j < 20; ++j) {
      int gk = kbase + kg + 8 * j;
      bool valid = (gk <= q) && (gk > q - wsz);
      s[j] = valid ? s[j] * 0.125f : -1e30f;
      m = fmaxf(m, s[j]);
    }
#pragma unroll
    for (int off = 1; off < 8; off <<= 1)
      m = fmaxf(m, __shfl_xor(m, off, 64));
    float l = 0.f;
#pragma unroll
    for (int j = 0; j < 20; ++j) {
      float e = (s[j] > -1e29f) ? __expf(s[j] - m) : 0.f;
      s[j] = e;
      l += e;
    }
#pragma unroll
    for (int off = 1; off < 8; off <<= 1)
      l += __shfl_xor(l, off, 64);
    float inv = 1.f / l;
#pragma unroll
    for (int j = 0; j < 20; ++j)
      Ps[qi][kg + 8 * j] = s[j] * inv;
  }
  __syncthreads();

  // ---- write FULL attnw rows, NON-TEMPORAL float4 streaming stores
  // (cached-path 16B stores showed 4x HBM write amplification; nt bypasses
  // L2 allocate and should stream full sectors)
  {
#pragma unroll
    for (int it = 0; it < 16; ++it) {
      int r = it * 2 + (tid >> 7);             // 0..31
      size_t rowoff = ((size_t)((b * NH + h) * LL + q0 + r)) * LL;
      int cb = (tid & 127) * 4;                // 0..508
#pragma unroll
      for (int jj = 0; jj < 4; ++jj) {
        int c4 = cb + jj * 512;
        f32x4 v = {0.f, 0.f, 0.f, 0.f};
        int pc = c4 - kbase;
        if (pc >= 0 && pc < KT)
          v = *(const f32x4*)&Ps[r][pc];
        __builtin_nontemporal_store(v, (f32x4*)&attnw[rowoff + c4]);
      }
    }
  }

  // ---- PV: V streamed from global, Ps read as float4
  {
    const int d = tid & 63;
    const int qb = tid >> 6;
    float acc[8] = {};
    const float* vbase = qkv + (size_t)(b * LL + kbase) * (3 * DM) + 2 * DM + h * HD + d;
#pragma unroll 2
    for (int kk4 = 0; kk4 < KT / 4; ++kk4) {
      float v0 = vbase[(size_t)(4 * kk4 + 0) * (3 * DM)];
      float v1 = vbase[(size_t)(4 * kk4 + 1) * (3 * DM)];
      float v2 = vbase[(size_t)(4 * kk4 + 2) * (3 * DM)];
      float v3 = vbase[(size_t)(4 * kk4 + 3) * (3 * DM)];
#pragma unroll
      for (int i = 0; i < 8; ++i) {
        float4 p = *(const float4*)&Ps[qb + 4 * i][kk4 * 4];
        acc[i] = fmaf(p.x, v0, fmaf(p.y, v1, fmaf(p.z, v2, fmaf(p.w, v3, acc[i]))));
      }
    }
#pragma unroll
    for (int i = 0; i < 8; ++i) {
      int qi = qb + 4 * i;
      ctxb[(size_t)(b * LL + q0 + qi) * DM + h * HD + d] = f2bf(acc[i]);
    }
  }
}

extern "C" void kernel_launch(void* const* d_in, const int* in_sizes, int n_in,
                              void* d_out, int out_size, void* d_ws, size_t ws_size,
                              hipStream_t stream) {
  const float* hs    = (const float*)d_in[0];
  const float* Wqkv  = (const float*)d_in[1];
  const float* bqkv  = (const float*)d_in[2];
  const float* Wproj = (const float*)d_in[3];
  const float* bproj = (const float*)d_in[4];
  const int*   wszp  = (const int*)d_in[5];

  float* out   = (float*)d_out;
  float* attnw = (float*)d_out + (size_t)BB * LL * DM;

  char* wsb = (char*)d_ws;
  float*    qkv    = (float*)wsb;                              // 50331648 B
  uint16_t* hsctxb = (uint16_t*)(wsb + 50331648);              //  8388608 B
  uint16_t* WqkvT  = (uint16_t*)(wsb + 50331648 + 8388608);    //  6291456 B
  uint16_t* WprojT = (uint16_t*)(wsb + 50331648 + 8388608 + 6291456);

  dim3 blk(256);

  cvt_bf16<<<dim3((BB * LL * DM / 4 + 255) / 256), blk, 0, stream>>>(hs, hsctxb, BB * LL * DM / 4);
  transpose_cvt<<<dim3(3 * DM / 32, DM / 32), blk, 0, stream>>>(Wqkv, WqkvT, DM, 3 * DM);
  transpose_cvt<<<dim3(DM / 32, DM / 32), blk, 0, stream>>>(Wproj, WprojT, DM, DM);

  gemm_bt_bf16<<<dim3(3 * DM / 128, BB * LL / 128), blk, 0, stream>>>(
      hsctxb, WqkvT, bqkv, qkv, BB * LL, 3 * DM, DM);

  attn_sw<<<dim3(BB * NH * (LL / QT)), blk, 0, stream>>>(qkv, attnw, hsctxb, wszp);

  gemm_bt_bf16<<<dim3(DM / 128, BB * LL / 128), blk, 0, stream>>>(
      hsctxb, WprojT, bproj, out, BB * LL, DM, DM);
}

// Round 6
// 638.249 us; speedup vs baseline: 1.8653x; 1.0897x over previous
//
#include <hip/hip_runtime.h>
#include <stdint.h>

#define NH 16
#define HD 64
#define DM 1024
#define BB 2
#define LL 2048

typedef __bf16 bf16x8 __attribute__((ext_vector_type(8)));
typedef float f32x4 __attribute__((ext_vector_type(4)));

__device__ __forceinline__ uint16_t f2bf(float f) {
  union { float f; uint32_t u; } x{f};
  uint32_t r = (x.u + 0x7fff + ((x.u >> 16) & 1)) >> 16;
  return (uint16_t)r;
}

__device__ __forceinline__ void gload_lds16(const void* g, void* l) {
  __builtin_amdgcn_global_load_lds(
      (const __attribute__((address_space(1))) unsigned int*)g,
      (__attribute__((address_space(3))) unsigned int*)l, 16, 0, 0);
}

// ---------------- fp32 -> bf16 cast (same layout)
__global__ __launch_bounds__(256) void cvt_bf16(
    const float* __restrict__ x, uint16_t* __restrict__ y, int n4) {
  int i = blockIdx.x * 256 + threadIdx.x;
  if (i >= n4) return;
  float4 v = ((const float4*)x)[i];
  ushort4 o;
  o.x = f2bf(v.x); o.y = f2bf(v.y); o.z = f2bf(v.z); o.w = f2bf(v.w);
  ((ushort4*)y)[i] = o;
}

// ---------------- fp32 [K,N] -> bf16 [N,K] transpose-cast
__global__ __launch_bounds__(256) void transpose_cvt(
    const float* __restrict__ W, uint16_t* __restrict__ WT, int K, int N) {
  __shared__ float t[32][33];
  int bk = blockIdx.y * 32, bn = blockIdx.x * 32;
  int c = threadIdx.x & 31, r0 = threadIdx.x >> 5;
#pragma unroll
  for (int p = 0; p < 4; ++p) {
    int r = r0 + p * 8;
    t[r][c] = W[(size_t)(bk + r) * N + bn + c];
  }
  __syncthreads();
#pragma unroll
  for (int p = 0; p < 4; ++p) {
    int r = r0 + p * 8;
    WT[(size_t)(bn + r) * K + bk + c] = f2bf(t[c][r]);
  }
}

// ---------------- bf16 MFMA GEMM: C[M,N] = A @ BT^T + bias
__global__ __launch_bounds__(256) void gemm_bt_bf16(
    const uint16_t* __restrict__ A, const uint16_t* __restrict__ BT,
    const float* __restrict__ bias, float* __restrict__ C,
    int M, int N, int K) {
  __shared__ uint16_t As[128 * 32];
  __shared__ uint16_t Bs[128 * 32];
  const int tid = threadIdx.x;
  const int bm = blockIdx.y * 128, bn = blockIdx.x * 128;
  const int lane = tid & 63, wave = tid >> 6;
  const int wr = wave >> 1, wc = wave & 1;
  f32x4 acc[4][4] = {};

  for (int k0 = 0; k0 < K; k0 += 32) {
#pragma unroll
    for (int c = 0; c < 2; ++c) {
      int e = c * 2048 + tid * 8;
      int r = e >> 5, col = e & 31;
      gload_lds16(A + (size_t)(bm + r) * K + k0 + col, (char*)As + (size_t)e * 2);
      gload_lds16(BT + (size_t)(bn + r) * K + k0 + col, (char*)Bs + (size_t)e * 2);
    }
    __syncthreads();

    const int kseg = (lane >> 4) * 8;
    bf16x8 af[4], bfr[4];
#pragma unroll
    for (int i = 0; i < 4; ++i)
      af[i] = *(const bf16x8*)&As[(wr * 64 + i * 16 + (lane & 15)) * 32 + kseg];
#pragma unroll
    for (int j = 0; j < 4; ++j)
      bfr[j] = *(const bf16x8*)&Bs[(wc * 64 + j * 16 + (lane & 15)) * 32 + kseg];
#pragma unroll
    for (int i = 0; i < 4; ++i)
#pragma unroll
      for (int j = 0; j < 4; ++j)
        acc[i][j] = __builtin_amdgcn_mfma_f32_16x16x32_bf16(af[i], bfr[j], acc[i][j], 0, 0, 0);
    __syncthreads();
  }

#pragma unroll
  for (int i = 0; i < 4; ++i) {
#pragma unroll
    for (int j = 0; j < 4; ++j) {
      int col = bn + wc * 64 + j * 16 + (lane & 15);
      float bv = bias[col];
#pragma unroll
      for (int r = 0; r < 4; ++r) {
        int row = bm + wr * 64 + i * 16 + (lane >> 4) * 4 + r;
        C[(size_t)row * N + col] = acc[i][j][r] + bv;
      }
    }
  }
}

// ---------------- MFMA sliding-window attention
// Per block: 32 q-rows, 160-key window (kbase 32-aligned). 4 waves.
// LDS 38.4 KB -> 4 blocks/CU (vs 65 KB / 2 blocks before).
// S = Q K^T via mfma 16x16x32 (bf16), softmax fp32, P -> LDS bf16,
// O = P V via mfma with V gathered from global as B-fragment.
#define QT 32
#define KT 160
#define KS 72    // Ks/Qs row stride (bf16): 144 B, 16B-aligned
#define PS 168   // Sf/Psb row stride: Sf 672 B, Psb 336 B

__global__ __launch_bounds__(256, 4) void attn_sw(
    const float* __restrict__ qkv,  // [B*L, 3*DM]
    float* __restrict__ attnw,      // [B,NH,L,L] - fully written here
    uint16_t* __restrict__ ctxb,    // [B*L, DM] bf16
    const int* __restrict__ wsz_p) {
  __shared__ __align__(16) char smemU[KT * KS * 2];     // Ksb (bf16) / Sf (f32)
  __shared__ __align__(16) uint16_t Qs[QT * KS];
  __shared__ __align__(16) uint16_t Psb[QT * PS];
  uint16_t* Ksb = (uint16_t*)smemU;   // [160][72] bf16
  float* Sf = (float*)smemU;          // [32][168] f32 (after K no longer needed)

  const int wsz = *wsz_p;  // 128
  const int tid = threadIdx.x;
  const int lane = tid & 63, wave = tid >> 6;
  const int ntile = LL / QT;
  const int qt = blockIdx.x % ntile;
  const int h = (blockIdx.x / ntile) % NH;
  const int b = blockIdx.x / (ntile * NH);
  const int q0 = qt * QT;
  const int kmin = max(0, q0 - (wsz - 1));
  const int kbase = kmin & ~31;  // 32-aligned; window rows always in-tensor

  // ---- P0: stage Q (32x64) and K (160x64) as bf16
  {
    int r = tid >> 3, c = (tid & 7) * 8;
    const float* src = qkv + (size_t)(b * LL + q0 + r) * (3 * DM) + h * HD + c;
    float4 a = *(const float4*)src, b4 = *(const float4*)(src + 4);
    uint16_t* dst = &Qs[r * KS + c];
    dst[0] = f2bf(a.x); dst[1] = f2bf(a.y); dst[2] = f2bf(a.z); dst[3] = f2bf(a.w);
    dst[4] = f2bf(b4.x); dst[5] = f2bf(b4.y); dst[6] = f2bf(b4.z); dst[7] = f2bf(b4.w);
  }
#pragma unroll
  for (int p = 0; p < 3; ++p) {
    int u = tid + p * 256;
    int r = u >> 2, c = (u & 3) * 16;
    if (r < KT) {
      const float* src = qkv + (size_t)(b * LL + kbase + r) * (3 * DM) + DM + h * HD + c;
      float4 a = *(const float4*)src, b4 = *(const float4*)(src + 4);
      float4 e = *(const float4*)(src + 8), f = *(const float4*)(src + 12);
      uint16_t* dst = &Ksb[r * KS + c];
      dst[0] = f2bf(a.x); dst[1] = f2bf(a.y); dst[2] = f2bf(a.z); dst[3] = f2bf(a.w);
      dst[4] = f2bf(b4.x); dst[5] = f2bf(b4.y); dst[6] = f2bf(b4.z); dst[7] = f2bf(b4.w);
      dst[8] = f2bf(e.x); dst[9] = f2bf(e.y); dst[10] = f2bf(e.z); dst[11] = f2bf(e.w);
      dst[12] = f2bf(f.x); dst[13] = f2bf(f.y); dst[14] = f2bf(f.z); dst[15] = f2bf(f.w);
    }
  }
  __syncthreads();

  // ---- P1a: S-fragments in registers. wave w: m-tile (w&1), n-tiles [(w>>1)*5 ..+5)
  const int mt = wave & 1, ntb = (wave >> 1) * 5;
  f32x4 sfrag[5];
  {
    const int kseg = (lane >> 4) * 8;
    bf16x8 aq0 = *(const bf16x8*)&Qs[(mt * 16 + (lane & 15)) * KS + kseg];
    bf16x8 aq1 = *(const bf16x8*)&Qs[(mt * 16 + (lane & 15)) * KS + 32 + kseg];
#pragma unroll
    for (int t = 0; t < 5; ++t) {
      int nt = ntb + t;
      bf16x8 bk0 = *(const bf16x8*)&Ksb[(nt * 16 + (lane & 15)) * KS + kseg];
      bf16x8 bk1 = *(const bf16x8*)&Ksb[(nt * 16 + (lane & 15)) * KS + 32 + kseg];
      f32x4 c = {0.f, 0.f, 0.f, 0.f};
      c = __builtin_amdgcn_mfma_f32_16x16x32_bf16(aq0, bk0, c, 0, 0, 0);
      c = __builtin_amdgcn_mfma_f32_16x16x32_bf16(aq1, bk1, c, 0, 0, 0);
      sfrag[t] = c;
    }
  }
  __syncthreads();  // Ksb reads done; Sf may now overwrite the union

  // ---- P1b: spill S-fragments to Sf (fp32)
#pragma unroll
  for (int t = 0; t < 5; ++t) {
    int nt = ntb + t;
#pragma unroll
    for (int r = 0; r < 4; ++r)
      Sf[(mt * 16 + (lane >> 4) * 4 + r) * PS + nt * 16 + (lane & 15)] = sfrag[t][r];
  }
  __syncthreads();

  // ---- P2: softmax (octet per q-row), probs -> Sf (f32) and Psb (bf16)
  {
    const int qi = tid >> 3;
    const int kg = tid & 7;
    const int q = q0 + qi;
    float s[20];
#pragma unroll
    for (int j = 0; j < 20; ++j) s[j] = Sf[qi * PS + kg + 8 * j];
    float m = -1e30f;
#pragma unroll
    for (int j = 0; j < 20; ++j) {
      int gk = kbase + kg + 8 * j;
      bool valid = (gk <= q) && (gk > q - wsz);
      s[j] = valid ? s[j] * 0.125f : -1e30f;
      m = fmaxf(m, s[j]);
    }
#pragma unroll
    for (int off = 1; off < 8; off <<= 1)
      m = fmaxf(m, __shfl_xor(m, off, 64));
    float l = 0.f;
#pragma unroll
    for (int j = 0; j < 20; ++j) {
      float e = (s[j] > -1e29f) ? __expf(s[j] - m) : 0.f;
      s[j] = e;
      l += e;
    }
#pragma unroll
    for (int off = 1; off < 8; off <<= 1)
      l += __shfl_xor(l, off, 64);
    float inv = 1.f / l;
#pragma unroll
    for (int j = 0; j < 20; ++j) {
      float p = s[j] * inv;
      Sf[qi * PS + kg + 8 * j] = p;
      Psb[qi * PS + kg + 8 * j] = f2bf(p);
    }
  }
  __syncthreads();

  // ---- P3: full attnw rows (zeros + band) from Sf, nt float4 stores.
  // Issued before PV so the HBM write stream overlaps the MFMA work.
  {
#pragma unroll
    for (int it = 0; it < 16; ++it) {
      int r = it * 2 + (tid >> 7);
      size_t rowoff = ((size_t)((b * NH + h) * LL + q0 + r)) * LL;
      int cb = (tid & 127) * 4;
#pragma unroll
      for (int jj = 0; jj < 4; ++jj) {
        int c4 = cb + jj * 512;
        f32x4 v = {0.f, 0.f, 0.f, 0.f};
        int pc = c4 - kbase;
        if (pc >= 0 && pc < KT)
          v = *(const f32x4*)&Sf[r * PS + pc];
        __builtin_nontemporal_store(v, (f32x4*)&attnw[rowoff + c4]);
      }
    }
  }

  // ---- P4: O = P V via MFMA. wave w: n-tile (d-cols) = w; both m-tiles.
  {
    const int nt = wave;           // d block: nt*16 + (lane&15)
    const int kseg = (lane >> 4) * 8;
    f32x4 ofrag[2] = {};
#pragma unroll
    for (int ks = 0; ks < 5; ++ks) {
      // B-fragment: V^T[d][key], gathered from global (fp32 -> bf16)
      const float* vs = qkv + (size_t)(b * LL + kbase + ks * 32 + kseg) * (3 * DM) +
                        2 * DM + h * HD + nt * 16 + (lane & 15);
      uint16_t vb[8];
#pragma unroll
      for (int j = 0; j < 8; ++j) vb[j] = f2bf(vs[(size_t)j * (3 * DM)]);
      bf16x8 bv = *(const bf16x8*)vb;
#pragma unroll
      for (int m = 0; m < 2; ++m) {
        bf16x8 ap = *(const bf16x8*)&Psb[(m * 16 + (lane & 15)) * PS + ks * 32 + kseg];
        ofrag[m] = __builtin_amdgcn_mfma_f32_16x16x32_bf16(ap, bv, ofrag[m], 0, 0, 0);
      }
    }
#pragma unroll
    for (int m = 0; m < 2; ++m)
#pragma unroll
      for (int r = 0; r < 4; ++r) {
        int q = q0 + m * 16 + (lane >> 4) * 4 + r;
        ctxb[(size_t)(b * LL + q) * DM + h * HD + nt * 16 + (lane & 15)] = f2bf(ofrag[m][r]);
      }
  }
}

extern "C" void kernel_launch(void* const* d_in, const int* in_sizes, int n_in,
                              void* d_out, int out_size, void* d_ws, size_t ws_size,
                              hipStream_t stream) {
  const float* hs    = (const float*)d_in[0];
  const float* Wqkv  = (const float*)d_in[1];
  const float* bqkv  = (const float*)d_in[2];
  const float* Wproj = (const float*)d_in[3];
  const float* bproj = (const float*)d_in[4];
  const int*   wszp  = (const int*)d_in[5];

  float* out   = (float*)d_out;
  float* attnw = (float*)d_out + (size_t)BB * LL * DM;

  char* wsb = (char*)d_ws;
  float*    qkv    = (float*)wsb;                              // 50331648 B
  uint16_t* hsctxb = (uint16_t*)(wsb + 50331648);              //  8388608 B
  uint16_t* WqkvT  = (uint16_t*)(wsb + 50331648 + 8388608);    //  6291456 B
  uint16_t* WprojT = (uint16_t*)(wsb + 50331648 + 8388608 + 6291456);

  dim3 blk(256);

  cvt_bf16<<<dim3((BB * LL * DM / 4 + 255) / 256), blk, 0, stream>>>(hs, hsctxb, BB * LL * DM / 4);
  transpose_cvt<<<dim3(3 * DM / 32, DM / 32), blk, 0, stream>>>(Wqkv, WqkvT, DM, 3 * DM);
  transpose_cvt<<<dim3(DM / 32, DM / 32), blk, 0, stream>>>(Wproj, WprojT, DM, DM);

  gemm_bt_bf16<<<dim3(3 * DM / 128, BB * LL / 128), blk, 0, stream>>>(
      hsctxb, WqkvT, bqkv, qkv, BB * LL, 3 * DM, DM);

  attn_sw<<<dim3(BB * NH * (LL / QT)), blk, 0, stream>>>(qkv, attnw, hsctxb, wszp);

  gemm_bt_bf16<<<dim3(DM / 128, BB * LL / 128), blk, 0, stream>>>(
      hsctxb, WprojT, bproj, out, BB * LL, DM, DM);
}